// Round 5
// baseline (590.845 us; speedup 1.0000x reference)
//
#include <hip/hip_runtime.h>

typedef unsigned short u16;
typedef short bf16x8 __attribute__((ext_vector_type(8)));
typedef float f32x4 __attribute__((ext_vector_type(4)));

// B=4, S=2048, E=1024, H=16, dk=64
#define SEQ   2048
#define EMB   1024
#define NH    16
#define DK    64

__device__ __forceinline__ u16 bf16_rne(float f) {
  union { float f; unsigned u; } x;
  x.f = f;
  unsigned u = x.u;
  u += 0x7fffu + ((u >> 16) & 1u);
  return (u16)(u >> 16);
}

// ---------------------------------------------------------------- fallback
__global__ __launch_bounds__(256) void fill_sig(float* __restrict__ out, int n) {
  const int i = blockIdx.x * 256 + threadIdx.x;
  if (i < n) out[i] = 1.0f;   // "workspace too small" signal
}

// ---------------------------------------------------------------- QKV GEMM
// C_z[M,1024] = x[M,1024] @ W_z   (x, W fp32 in global; bf16 in LDS/MFMA)
// out layout: head [((b*16+h)*2048+s)*64+d], z==0 (Q) scaled by 0.125.
#define BSTR 40   // Bs stride (u16): %8==0 keeps frag reads 16B-aligned
__global__ __launch_bounds__(256) void gemm_qkv(
    const float* __restrict__ A,
    const float* __restrict__ W0, const float* __restrict__ W1, const float* __restrict__ W2,
    u16* __restrict__ C0, u16* __restrict__ C1, u16* __restrict__ C2)
{
  const int z = blockIdx.z;
  const float* Wm = (z == 0) ? W0 : (z == 1) ? W1 : W2;
  u16* C = (z == 0) ? C0 : (z == 1) ? C1 : C2;
  const float scale = (z == 0) ? 0.125f : 1.0f;

  __shared__ __align__(16) u16 As[128 * 32];
  __shared__ __align__(16) u16 Bs[128 * BSTR];

  const int tid  = threadIdx.x;
  const int lane = tid & 63;
  const int w    = tid >> 6;
  const int wm   = (w >> 1) * 64;
  const int wn   = (w & 1) * 64;
  const int m0   = blockIdx.x * 128;
  const int n0   = blockIdx.y * 128;

  const int l15  = lane & 15;
  const int g8   = (lane >> 4) * 8;

  const int srow0 = tid >> 2;           // 0..63
  const int skc   = (tid & 3) * 8;      // 0,8,16,24 (float index)

  const int bk  = tid & 31;             // k within tile
  const int bn0 = (tid >> 5) * 16;      // n offset: 0..112

  f32x4 acc[4][4] = {};

  for (int k0 = 0; k0 < 1024; k0 += 32) {
    // ---- global f32 -> regs
    float4 a00 = *(const float4*)(A + (size_t)(m0 + srow0) * 1024 + k0 + skc);
    float4 a01 = *(const float4*)(A + (size_t)(m0 + srow0) * 1024 + k0 + skc + 4);
    float4 a10 = *(const float4*)(A + (size_t)(m0 + srow0 + 64) * 1024 + k0 + skc);
    float4 a11 = *(const float4*)(A + (size_t)(m0 + srow0 + 64) * 1024 + k0 + skc + 4);
    const float* gw = Wm + (size_t)(k0 + bk) * 1024 + n0 + bn0;
    float4 w0 = ((const float4*)gw)[0];
    float4 w1 = ((const float4*)gw)[1];
    float4 w2 = ((const float4*)gw)[2];
    float4 w3 = ((const float4*)gw)[3];

    // ---- convert + LDS store
    union { int4 v; u16 h[8]; } c0, c1;
    c0.h[0] = bf16_rne(a00.x); c0.h[1] = bf16_rne(a00.y);
    c0.h[2] = bf16_rne(a00.z); c0.h[3] = bf16_rne(a00.w);
    c0.h[4] = bf16_rne(a01.x); c0.h[5] = bf16_rne(a01.y);
    c0.h[6] = bf16_rne(a01.z); c0.h[7] = bf16_rne(a01.w);
    c1.h[0] = bf16_rne(a10.x); c1.h[1] = bf16_rne(a10.y);
    c1.h[2] = bf16_rne(a10.z); c1.h[3] = bf16_rne(a10.w);
    c1.h[4] = bf16_rne(a11.x); c1.h[5] = bf16_rne(a11.y);
    c1.h[6] = bf16_rne(a11.z); c1.h[7] = bf16_rne(a11.w);
    *(int4*)(As + srow0 * 32 + skc) = c0.v;
    *(int4*)(As + (srow0 + 64) * 32 + skc) = c1.v;

    const float wf[16] = { w0.x, w0.y, w0.z, w0.w, w1.x, w1.y, w1.z, w1.w,
                           w2.x, w2.y, w2.z, w2.w, w3.x, w3.y, w3.z, w3.w };
#pragma unroll
    for (int e = 0; e < 16; ++e)
      Bs[(bn0 + e) * BSTR + bk] = bf16_rne(wf[e]);

    __syncthreads();
    bf16x8 a[4], b[4];
#pragma unroll
    for (int mi = 0; mi < 4; ++mi)
      a[mi] = *(const bf16x8*)(As + (wm + mi * 16 + l15) * 32 + g8);
#pragma unroll
    for (int ni = 0; ni < 4; ++ni)
      b[ni] = *(const bf16x8*)(Bs + (wn + ni * 16 + l15) * BSTR + g8);
#pragma unroll
    for (int mi = 0; mi < 4; ++mi)
#pragma unroll
      for (int ni = 0; ni < 4; ++ni)
        acc[mi][ni] = __builtin_amdgcn_mfma_f32_16x16x32_bf16(a[mi], b[ni], acc[mi][ni], 0, 0, 0);
    __syncthreads();
  }

  const int rb = (lane >> 4) * 4;
#pragma unroll
  for (int mi = 0; mi < 4; ++mi) {
#pragma unroll
    for (int r = 0; r < 4; ++r) {
      const int row = m0 + wm + mi * 16 + rb + r;
      const int bb = row >> 11, s = row & 2047;
#pragma unroll
      for (int ni = 0; ni < 4; ++ni) {
        const int col = n0 + wn + ni * 16 + l15;
        const int hh = col >> 6, d = col & 63;
        C[((size_t)(bb * NH + hh) * SEQ + s) * DK + d] = bf16_rne(acc[mi][ni][r] * scale);
      }
    }
  }
}

// ---------------------------------------------------------------- out GEMM
// out[M,1024] (fp32) = Ob[M,1024] (bf16) @ WO (fp32)
__global__ __launch_bounds__(256) void gemm_out(
    const u16* __restrict__ A, const float* __restrict__ Wm, float* __restrict__ C)
{
  __shared__ __align__(16) u16 As[128 * 32];
  __shared__ __align__(16) u16 Bs[128 * BSTR];

  const int tid  = threadIdx.x;
  const int lane = tid & 63;
  const int w    = tid >> 6;
  const int wm   = (w >> 1) * 64;
  const int wn   = (w & 1) * 64;
  const int m0   = blockIdx.x * 128;
  const int n0   = blockIdx.y * 128;

  const int l15  = lane & 15;
  const int g8   = (lane >> 4) * 8;

  const int srow0 = tid >> 2;
  const int skc   = (tid & 3) * 8;

  const int bk  = tid & 31;
  const int bn0 = (tid >> 5) * 16;

  f32x4 acc[4][4] = {};

  for (int k0 = 0; k0 < 1024; k0 += 32) {
    int4 a0 = *(const int4*)(A + (size_t)(m0 + srow0) * 1024 + k0 + skc);
    int4 a1 = *(const int4*)(A + (size_t)(m0 + srow0 + 64) * 1024 + k0 + skc);
    const float* gw = Wm + (size_t)(k0 + bk) * 1024 + n0 + bn0;
    float4 w0 = ((const float4*)gw)[0];
    float4 w1 = ((const float4*)gw)[1];
    float4 w2 = ((const float4*)gw)[2];
    float4 w3 = ((const float4*)gw)[3];

    *(int4*)(As + srow0 * 32 + skc) = a0;
    *(int4*)(As + (srow0 + 64) * 32 + skc) = a1;
    const float wf[16] = { w0.x, w0.y, w0.z, w0.w, w1.x, w1.y, w1.z, w1.w,
                           w2.x, w2.y, w2.z, w2.w, w3.x, w3.y, w3.z, w3.w };
#pragma unroll
    for (int e = 0; e < 16; ++e)
      Bs[(bn0 + e) * BSTR + bk] = bf16_rne(wf[e]);

    __syncthreads();
    bf16x8 a[4], b[4];
#pragma unroll
    for (int mi = 0; mi < 4; ++mi)
      a[mi] = *(const bf16x8*)(As + (wm + mi * 16 + l15) * 32 + g8);
#pragma unroll
    for (int ni = 0; ni < 4; ++ni)
      b[ni] = *(const bf16x8*)(Bs + (wn + ni * 16 + l15) * BSTR + g8);
#pragma unroll
    for (int mi = 0; mi < 4; ++mi)
#pragma unroll
      for (int ni = 0; ni < 4; ++ni)
        acc[mi][ni] = __builtin_amdgcn_mfma_f32_16x16x32_bf16(a[mi], b[ni], acc[mi][ni], 0, 0, 0);
    __syncthreads();
  }

  const int rb = (lane >> 4) * 4;
#pragma unroll
  for (int mi = 0; mi < 4; ++mi) {
#pragma unroll
    for (int r = 0; r < 4; ++r) {
      const int row = m0 + wm + mi * 16 + rb + r;
#pragma unroll
      for (int ni = 0; ni < 4; ++ni) {
        const int col = n0 + wn + ni * 16 + l15;
        C[(size_t)row * 1024 + col] = acc[mi][ni][r];
      }
    }
  }
}

// ---------------------------------------------------------------- attention
// Q,K,V: [B*H, S, 64] bf16 (Q pre-scaled by 0.125). O: [B*S, E] bf16.
__global__ __launch_bounds__(256) void attn64(
    const u16* __restrict__ Q, const u16* __restrict__ K, const u16* __restrict__ V,
    u16* __restrict__ O)
{
  const int qt  = gridDim.x - 1 - blockIdx.x;   // heavy tiles first
  const int bh  = blockIdx.y;
  const int tid = threadIdx.x;
  const int lane = tid & 63;
  const int w    = tid >> 6;

  const size_t base = (size_t)bh * SEQ * DK;
  const u16* Qp = Q + base;
  const u16* Kp = K + base;
  const u16* Vp = V + base;

  __shared__ __align__(16) u16 Vt[64 * 72];       // [d][key], stride 72
  __shared__ __align__(16) u16 Pt[4][16 * 72];    // per-wave [qrow][key]

  const int l15 = lane & 15;
  const int g   = lane >> 4;
  const int g8  = g * 8;
  const int q0  = qt * 64 + w * 16;

  bf16x8 qf[2];
#pragma unroll
  for (int kk = 0; kk < 2; ++kk)
    qf[kk] = *(const bf16x8*)(Qp + (size_t)(q0 + l15) * DK + kk * 32 + g8);

  f32x4 o[4] = {};
  float mrun = -1e30f, lrun = 0.f;

  u16* pw = &Pt[w][0];

  for (int t = 0; t <= qt; ++t) {
#pragma unroll
    for (int i = 0; i < 2; ++i) {
      const int c = tid + i * 256;
      const int key = c >> 3, d8 = (c & 7) * 8;
      union { int4 v; u16 u[8]; } uu;
      uu.v = *(const int4*)(Vp + (size_t)(t * 64 + key) * DK + d8);
#pragma unroll
      for (int e = 0; e < 8; ++e)
        Vt[(d8 + e) * 72 + key] = uu.u[e];
    }
    __syncthreads();

    f32x4 st[4] = {};
#pragma unroll
    for (int kk = 0; kk < 2; ++kk) {
#pragma unroll
      for (int mt = 0; mt < 4; ++mt) {
        const bf16x8 kf = *(const bf16x8*)(Kp + (size_t)(t * 64 + mt * 16 + l15) * DK + kk * 32 + g8);
        st[mt] = __builtin_amdgcn_mfma_f32_16x16x32_bf16(kf, qf[kk], st[mt], 0, 0, 0);
      }
    }

    if (t == qt) {
      const int qrow = q0 + l15;
#pragma unroll
      for (int mt = 0; mt < 4; ++mt)
#pragma unroll
        for (int r = 0; r < 4; ++r)
          if (qt * 64 + mt * 16 + g * 4 + r > qrow) st[mt][r] = -1e30f;
    }

    float tmax = -1e30f;
#pragma unroll
    for (int mt = 0; mt < 4; ++mt)
#pragma unroll
      for (int r = 0; r < 4; ++r) tmax = fmaxf(tmax, st[mt][r]);
    tmax = fmaxf(tmax, __shfl_xor(tmax, 16));
    tmax = fmaxf(tmax, __shfl_xor(tmax, 32));

    const float mnew  = fmaxf(mrun, tmax);
    const float alpha = __expf(mrun - mnew);
    mrun = mnew;

    float psum = 0.f;
#pragma unroll
    for (int mt = 0; mt < 4; ++mt) {
#pragma unroll
      for (int r = 0; r < 4; ++r) {
        const float p = __expf(st[mt][r] - mnew);
        psum += p;
        pw[l15 * 72 + mt * 16 + g * 4 + r] = bf16_rne(p);
      }
    }
    psum += __shfl_xor(psum, 16);
    psum += __shfl_xor(psum, 32);
    lrun = lrun * alpha + psum;

#pragma unroll
    for (int r = 0; r < 4; ++r) {
      const float ar = __shfl(alpha, g * 4 + r);
#pragma unroll
      for (int nt = 0; nt < 4; ++nt) o[nt][r] *= ar;
    }

    __syncthreads();

#pragma unroll
    for (int kk = 0; kk < 2; ++kk) {
      const bf16x8 pa = *(const bf16x8*)(pw + l15 * 72 + kk * 32 + g8);
#pragma unroll
      for (int nt = 0; nt < 4; ++nt) {
        const bf16x8 vb = *(const bf16x8*)(Vt + (nt * 16 + l15) * 72 + kk * 32 + g8);
        o[nt] = __builtin_amdgcn_mfma_f32_16x16x32_bf16(pa, vb, o[nt], 0, 0, 0);
      }
    }
    __syncthreads();
  }

  const int b_ = bh >> 4, h_ = bh & 15;
#pragma unroll
  for (int r = 0; r < 4; ++r) {
    const float lr  = __shfl(lrun, g * 4 + r);
    const float inv = 1.0f / lr;
    const int   s   = q0 + g * 4 + r;
#pragma unroll
    for (int nt = 0; nt < 4; ++nt) {
      const int d = nt * 16 + l15;
      O[((size_t)b_ * SEQ + s) * EMB + h_ * DK + d] = bf16_rne(o[nt][r] * inv);
    }
  }
}

// ---------------------------------------------------------------- launch
extern "C" void kernel_launch(void* const* d_in, const int* in_sizes, int n_in,
                              void* d_out, int out_size, void* d_ws, size_t ws_size,
                              hipStream_t stream) {
  (void)in_sizes; (void)n_in;
  const float* x  = (const float*)d_in[0];
  const float* WQ = (const float*)d_in[1];
  const float* WK = (const float*)d_in[2];
  const float* WV = (const float*)d_in[3];
  const float* WO = (const float*)d_in[4];
  float* out = (float*)d_out;

  const size_t MTOK = (size_t)4 * SEQ;        // 8192 rows
  const size_t NTOK = MTOK * EMB;             // 8,388,608 elements

  const size_t NEEDED = 4 * NTOK * sizeof(u16);   // 64 MiB: Q,K,V,Ob (bf16)
  if (ws_size < NEEDED) {
    fill_sig<<<dim3((out_size + 255) / 256), 256, 0, stream>>>(out, out_size);
    return;
  }

  u16* ws  = (u16*)d_ws;
  u16* Qb  = ws;
  u16* Kb  = Qb + NTOK;
  u16* Vb  = Kb + NTOK;
  u16* Ob  = Vb + NTOK;

  gemm_qkv<<<dim3(MTOK / 128, EMB / 128, 3), 256, 0, stream>>>(
      x, WQ, WK, WV, Qb, Kb, Vb);
  attn64<<<dim3(SEQ / 64, 4 * NH), 256, 0, stream>>>(Qb, Kb, Vb, Ob);
  gemm_out<<<dim3(MTOK / 128, EMB / 128), 256, 0, stream>>>(Ob, WO, out);
}

// Round 6
// 548.925 us; speedup vs baseline: 1.0764x; 1.0764x over previous
//
#include <hip/hip_runtime.h>

typedef unsigned short u16;
typedef short bf16x8 __attribute__((ext_vector_type(8)));
typedef float f32x4 __attribute__((ext_vector_type(4)));

// B=4, S=2048, E=1024, H=16, dk=64
#define SEQ   2048
#define EMB   1024
#define NH    16
#define DK    64

// softmax done in base-2: Q pre-scaled by 0.125 * log2(e)
#define QSCALE 0.1803368801111144f

__device__ __forceinline__ u16 bf16_rne(float f) {
  union { float f; unsigned u; } x;
  x.f = f;
  unsigned u = x.u;
  u += 0x7fffu + ((u >> 16) & 1u);
  return (u16)(u >> 16);
}

// ---------------------------------------------------------------- fallback
__global__ __launch_bounds__(256) void fill_sig(float* __restrict__ out, int n) {
  const int i = blockIdx.x * 256 + threadIdx.x;
  if (i < n) out[i] = 1.0f;   // "workspace too small" signal
}

// ---------------------------------------------------------------- QKV GEMM
// C_z[M,1024] = x[M,1024] @ W_z   (x, W fp32 in global; bf16 in LDS/MFMA)
// z==0 (Q): head layout [((b*16+h)*2048+s)*64+d], scaled by QSCALE
// z==1 (K): head layout, unscaled
// z==2 (V): TRANSPOSED layout [((b*16+h)*64+d)*2048 + s]  (via LDS transpose)
#define BSTR 40   // Bs stride (u16): %8==0 keeps frag reads 16B-aligned
__global__ __launch_bounds__(256) void gemm_qkv(
    const float* __restrict__ A,
    const float* __restrict__ W0, const float* __restrict__ W1, const float* __restrict__ W2,
    u16* __restrict__ C0, u16* __restrict__ C1, u16* __restrict__ C2)
{
  const int z = blockIdx.z;
  const float* Wm = (z == 0) ? W0 : (z == 1) ? W1 : W2;
  u16* C = (z == 0) ? C0 : (z == 1) ? C1 : C2;
  const float scale = (z == 0) ? QSCALE : 1.0f;

  __shared__ __align__(16) u16 sh[9216];   // As(128*32) + Bs(128*40); reused as T(64*136)
  u16* const As = sh;
  u16* const Bs = sh + 128 * 32;

  const int tid  = threadIdx.x;
  const int lane = tid & 63;
  const int w    = tid >> 6;
  const int wm   = (w >> 1) * 64;
  const int wn   = (w & 1) * 64;
  const int m0   = blockIdx.x * 128;
  const int n0   = blockIdx.y * 128;

  const int l15  = lane & 15;
  const int g8   = (lane >> 4) * 8;

  const int srow0 = tid >> 2;           // 0..63
  const int skc   = (tid & 3) * 8;      // 0,8,16,24 (float index)

  const int bk  = tid & 31;             // k within tile
  const int bn0 = (tid >> 5) * 16;      // n offset: 0..112

  f32x4 acc[4][4] = {};

  for (int k0 = 0; k0 < 1024; k0 += 32) {
    // ---- global f32 -> regs
    float4 a00 = *(const float4*)(A + (size_t)(m0 + srow0) * 1024 + k0 + skc);
    float4 a01 = *(const float4*)(A + (size_t)(m0 + srow0) * 1024 + k0 + skc + 4);
    float4 a10 = *(const float4*)(A + (size_t)(m0 + srow0 + 64) * 1024 + k0 + skc);
    float4 a11 = *(const float4*)(A + (size_t)(m0 + srow0 + 64) * 1024 + k0 + skc + 4);
    const float* gw = Wm + (size_t)(k0 + bk) * 1024 + n0 + bn0;
    float4 w0 = ((const float4*)gw)[0];
    float4 w1 = ((const float4*)gw)[1];
    float4 w2 = ((const float4*)gw)[2];
    float4 w3 = ((const float4*)gw)[3];

    // ---- convert + LDS store
    union { int4 v; u16 h[8]; } c0, c1;
    c0.h[0] = bf16_rne(a00.x); c0.h[1] = bf16_rne(a00.y);
    c0.h[2] = bf16_rne(a00.z); c0.h[3] = bf16_rne(a00.w);
    c0.h[4] = bf16_rne(a01.x); c0.h[5] = bf16_rne(a01.y);
    c0.h[6] = bf16_rne(a01.z); c0.h[7] = bf16_rne(a01.w);
    c1.h[0] = bf16_rne(a10.x); c1.h[1] = bf16_rne(a10.y);
    c1.h[2] = bf16_rne(a10.z); c1.h[3] = bf16_rne(a10.w);
    c1.h[4] = bf16_rne(a11.x); c1.h[5] = bf16_rne(a11.y);
    c1.h[6] = bf16_rne(a11.z); c1.h[7] = bf16_rne(a11.w);
    *(int4*)(As + srow0 * 32 + skc) = c0.v;
    *(int4*)(As + (srow0 + 64) * 32 + skc) = c1.v;

    const float wf[16] = { w0.x, w0.y, w0.z, w0.w, w1.x, w1.y, w1.z, w1.w,
                           w2.x, w2.y, w2.z, w2.w, w3.x, w3.y, w3.z, w3.w };
#pragma unroll
    for (int e = 0; e < 16; ++e)
      Bs[(bn0 + e) * BSTR + bk] = bf16_rne(wf[e]);

    __syncthreads();
    bf16x8 a[4], b[4];
#pragma unroll
    for (int mi = 0; mi < 4; ++mi)
      a[mi] = *(const bf16x8*)(As + (wm + mi * 16 + l15) * 32 + g8);
#pragma unroll
    for (int ni = 0; ni < 4; ++ni)
      b[ni] = *(const bf16x8*)(Bs + (wn + ni * 16 + l15) * BSTR + g8);
#pragma unroll
    for (int mi = 0; mi < 4; ++mi)
#pragma unroll
      for (int ni = 0; ni < 4; ++ni)
        acc[mi][ni] = __builtin_amdgcn_mfma_f32_16x16x32_bf16(a[mi], b[ni], acc[mi][ni], 0, 0, 0);
    __syncthreads();
  }

  const int rb = (lane >> 4) * 4;

  if (z != 2) {
    // head layout write
#pragma unroll
    for (int mi = 0; mi < 4; ++mi) {
#pragma unroll
      for (int r = 0; r < 4; ++r) {
        const int row = m0 + wm + mi * 16 + rb + r;
        const int bb = row >> 11, s = row & 2047;
#pragma unroll
        for (int ni = 0; ni < 4; ++ni) {
          const int col = n0 + wn + ni * 16 + l15;
          const int hh = col >> 6, d = col & 63;
          C[((size_t)(bb * NH + hh) * SEQ + s) * DK + d] = bf16_rne(acc[mi][ni][r] * scale);
        }
      }
    }
  } else {
    // V: transposed write via LDS. Tile covers heads (n0>>6)+{0,1}; wave half
    // w&1 owns cols (w&1)*64..+64 (head (n0>>6)+(w&1)).
    const int bb = m0 >> 11;
    const int s0 = m0 & 2047;
    u16* const T = sh;   // 64 x 136, XOR-swizzled along s
    const int dRd  = tid >> 2;           // read phase: d row 0..63
    const int cbRd = (tid & 3) * 32;     // s chunk base
    const int swzR = ((dRd >> 3) & 7) << 3;
#pragma unroll
    for (int p = 0; p < 2; ++p) {
      if ((w & 1) == p) {
#pragma unroll
        for (int mi = 0; mi < 4; ++mi)
#pragma unroll
          for (int r = 0; r < 4; ++r) {
            const int s_local = wm + mi * 16 + rb + r;
#pragma unroll
            for (int ni = 0; ni < 4; ++ni) {
              const int d = ni * 16 + l15;
              T[d * 136 + (s_local ^ (((d >> 3) & 7) << 3))] = bf16_rne(acc[mi][ni][r]);
            }
          }
      }
      __syncthreads();
      u16* dst = C + ((size_t)(bb * NH + (n0 >> 6) + p) * DK + dRd) * SEQ + s0 + cbRd;
#pragma unroll
      for (int k = 0; k < 4; ++k) {
        int4 v = *(const int4*)(T + dRd * 136 + ((cbRd + 8 * k) ^ swzR));
        *(int4*)(dst + 8 * k) = v;
      }
      __syncthreads();
    }
  }
}

// ---------------------------------------------------------------- out GEMM
// out[M,1024] (fp32) = Ob[M,1024] (bf16) @ WO (fp32)
__global__ __launch_bounds__(256) void gemm_out(
    const u16* __restrict__ A, const float* __restrict__ Wm, float* __restrict__ C)
{
  __shared__ __align__(16) u16 As[128 * 32];
  __shared__ __align__(16) u16 Bs[128 * BSTR];

  const int tid  = threadIdx.x;
  const int lane = tid & 63;
  const int w    = tid >> 6;
  const int wm   = (w >> 1) * 64;
  const int wn   = (w & 1) * 64;
  const int m0   = blockIdx.x * 128;
  const int n0   = blockIdx.y * 128;

  const int l15  = lane & 15;
  const int g8   = (lane >> 4) * 8;

  const int srow0 = tid >> 2;
  const int skc   = (tid & 3) * 8;

  const int bk  = tid & 31;
  const int bn0 = (tid >> 5) * 16;

  f32x4 acc[4][4] = {};

  for (int k0 = 0; k0 < 1024; k0 += 32) {
    int4 a0 = *(const int4*)(A + (size_t)(m0 + srow0) * 1024 + k0 + skc);
    int4 a1 = *(const int4*)(A + (size_t)(m0 + srow0 + 64) * 1024 + k0 + skc);
    const float* gw = Wm + (size_t)(k0 + bk) * 1024 + n0 + bn0;
    float4 w0 = ((const float4*)gw)[0];
    float4 w1 = ((const float4*)gw)[1];
    float4 w2 = ((const float4*)gw)[2];
    float4 w3 = ((const float4*)gw)[3];

    *(int4*)(As + srow0 * 32 + skc) = a0;
    *(int4*)(As + (srow0 + 64) * 32 + skc) = a1;
    const float wf[16] = { w0.x, w0.y, w0.z, w0.w, w1.x, w1.y, w1.z, w1.w,
                           w2.x, w2.y, w2.z, w2.w, w3.x, w3.y, w3.z, w3.w };
#pragma unroll
    for (int e = 0; e < 16; ++e)
      Bs[(bn0 + e) * BSTR + bk] = bf16_rne(wf[e]);

    __syncthreads();
    bf16x8 a[4], b[4];
#pragma unroll
    for (int mi = 0; mi < 4; ++mi)
      a[mi] = *(const bf16x8*)(As + (wm + mi * 16 + l15) * 32 + g8);
#pragma unroll
    for (int ni = 0; ni < 4; ++ni)
      b[ni] = *(const bf16x8*)(Bs + (wn + ni * 16 + l15) * BSTR + g8);
#pragma unroll
    for (int mi = 0; mi < 4; ++mi)
#pragma unroll
      for (int ni = 0; ni < 4; ++ni)
        acc[mi][ni] = __builtin_amdgcn_mfma_f32_16x16x32_bf16(a[mi], b[ni], acc[mi][ni], 0, 0, 0);
    __syncthreads();
  }

  const int rb = (lane >> 4) * 4;
#pragma unroll
  for (int mi = 0; mi < 4; ++mi) {
#pragma unroll
    for (int r = 0; r < 4; ++r) {
      const int row = m0 + wm + mi * 16 + rb + r;
#pragma unroll
      for (int ni = 0; ni < 4; ++ni) {
        const int col = n0 + wn + ni * 16 + l15;
        C[(size_t)row * 1024 + col] = acc[mi][ni][r];
      }
    }
  }
}

// ---------------------------------------------------------------- attention
// Q,K: [B*H, S, 64] bf16 (Q pre-scaled by QSCALE, base-2 softmax).
// VT: [B*H, 64, S] bf16 (pre-transposed V). O: [B*S, E] bf16.
// Block: 64 q-rows, 4 waves x 16 rows; KV tiles of 64; 2 barriers/t.
__global__ __launch_bounds__(256) void attn64(
    const u16* __restrict__ Q, const u16* __restrict__ K, const u16* __restrict__ VT,
    u16* __restrict__ O)
{
  const int qt  = gridDim.x - 1 - blockIdx.x;   // heavy tiles first
  const int bh  = blockIdx.y;
  const int tid = threadIdx.x;
  const int lane = tid & 63;
  const int w    = tid >> 6;

  const u16* Qp = Q  + (size_t)bh * SEQ * DK;
  const u16* Kp = K  + (size_t)bh * SEQ * DK;
  const u16* Vp = VT + (size_t)bh * DK * SEQ;   // [d][s]

  __shared__ __align__(16) u16 Vt[64 * 72];     // [d][key], stride 72 (144B rows)
  __shared__ __align__(16) u16 Pt[4][16 * 72];  // per-wave [qrow][key]

  const int l15 = lane & 15;
  const int g   = lane >> 4;
  const int g8  = g * 8;
  const int q0  = qt * 64 + w * 16;

  // Vt staging map: thread covers rows (tid>>3) and (tid>>3)+32, 16B each
  const int vrow = tid >> 3;        // 0..31
  const int vk8  = (tid & 7) * 8;   // 0..56

  bf16x8 qf[2];
#pragma unroll
  for (int kk = 0; kk < 2; ++kk)
    qf[kk] = *(const bf16x8*)(Qp + (size_t)(q0 + l15) * DK + kk * 32 + g8);

  f32x4 o[4] = {};                   // O[16 q][64 d], C-layout (row=q=g*4+r)
  float mrun = -1e30f, lrun = 0.f;   // stats for qrow = q0 + l15 (base-2)

  u16* const pw = &Pt[w][0];

  for (int t = 0; t <= qt; ++t) {
    // ---- cooperative Vt stage: straight b128 copy from pre-transposed VT
    {
      const u16* src = Vp + (size_t)vrow * SEQ + t * 64 + vk8;
      int4 v0 = *(const int4*)(src);
      int4 v1 = *(const int4*)(src + (size_t)32 * SEQ);
      *(int4*)(Vt + vrow * 72 + vk8) = v0;
      *(int4*)(Vt + (vrow + 32) * 72 + vk8) = v1;
    }
    __syncthreads();   // Vt visible (also guards prior-iter reads: see end barrier)

    // ---- S^T = K . Q^T : m=key (4x16), n=q (16)
    f32x4 st[4] = {};
#pragma unroll
    for (int kk = 0; kk < 2; ++kk) {
#pragma unroll
      for (int mt = 0; mt < 4; ++mt) {
        const bf16x8 kf = *(const bf16x8*)(Kp + (size_t)(t * 64 + mt * 16 + l15) * DK + kk * 32 + g8);
        st[mt] = __builtin_amdgcn_mfma_f32_16x16x32_bf16(kf, qf[kk], st[mt], 0, 0, 0);
      }
    }

    if (t == qt) {                   // causal mask on diagonal tile
      const int qrow = q0 + l15;
#pragma unroll
      for (int mt = 0; mt < 4; ++mt)
#pragma unroll
        for (int r = 0; r < 4; ++r)
          if (qt * 64 + mt * 16 + g * 4 + r > qrow) st[mt][r] = -1e30f;
    }

    // ---- online softmax (base-2), stats per q = l15
    float tmax = -1e30f;
#pragma unroll
    for (int mt = 0; mt < 4; ++mt)
#pragma unroll
      for (int r = 0; r < 4; ++r) tmax = fmaxf(tmax, st[mt][r]);
    tmax = fmaxf(tmax, __shfl_xor(tmax, 16));
    tmax = fmaxf(tmax, __shfl_xor(tmax, 32));

    const float mnew  = fmaxf(mrun, tmax);
    const float alpha = exp2f(mrun - mnew);
    mrun = mnew;

    float psum = 0.f;
#pragma unroll
    for (int mt = 0; mt < 4; ++mt) {
      float p0 = exp2f(st[mt][0] - mnew);
      float p1 = exp2f(st[mt][1] - mnew);
      float p2 = exp2f(st[mt][2] - mnew);
      float p3 = exp2f(st[mt][3] - mnew);
      psum += (p0 + p1) + (p2 + p3);
      uint2 pk;
      pk.x = (unsigned)bf16_rne(p0) | ((unsigned)bf16_rne(p1) << 16);
      pk.y = (unsigned)bf16_rne(p2) | ((unsigned)bf16_rne(p3) << 16);
      *(uint2*)(pw + l15 * 72 + mt * 16 + g * 4) = pk;   // P[q=l15][key]
    }
    psum += __shfl_xor(psum, 16);
    psum += __shfl_xor(psum, 32);
    lrun = lrun * alpha + psum;

    // rescale O (alpha indexed by q=l15; O rows are q=g*4+r)
#pragma unroll
    for (int r = 0; r < 4; ++r) {
      const float ar = __shfl(alpha, g * 4 + r);
#pragma unroll
      for (int nt = 0; nt < 4; ++nt) o[nt][r] *= ar;
    }

    // ---- O += P . V  (Pt same-wave RAW: lgkmcnt only, no barrier)
#pragma unroll
    for (int kk = 0; kk < 2; ++kk) {
      const bf16x8 pa = *(const bf16x8*)(pw + l15 * 72 + kk * 32 + g8);
#pragma unroll
      for (int nt = 0; nt < 4; ++nt) {
        const bf16x8 vb = *(const bf16x8*)(Vt + (nt * 16 + l15) * 72 + kk * 32 + g8);
        o[nt] = __builtin_amdgcn_mfma_f32_16x16x32_bf16(pa, vb, o[nt], 0, 0, 0);
      }
    }
    __syncthreads();   // all Vt reads done before next stage overwrites
  }

  // epilogue: O[q][d] / l  -> Ob[b][s][h*64+d]
  const int b_ = bh >> 4, h_ = bh & 15;
#pragma unroll
  for (int r = 0; r < 4; ++r) {
    const float lr  = __shfl(lrun, g * 4 + r);
    const float inv = 1.0f / lr;
    const int   s   = q0 + g * 4 + r;
#pragma unroll
    for (int nt = 0; nt < 4; ++nt) {
      const int d = nt * 16 + l15;
      O[((size_t)b_ * SEQ + s) * EMB + h_ * DK + d] = bf16_rne(o[nt][r] * inv);
    }
  }
}

// ---------------------------------------------------------------- launch
extern "C" void kernel_launch(void* const* d_in, const int* in_sizes, int n_in,
                              void* d_out, int out_size, void* d_ws, size_t ws_size,
                              hipStream_t stream) {
  (void)in_sizes; (void)n_in;
  const float* x  = (const float*)d_in[0];
  const float* WQ = (const float*)d_in[1];
  const float* WK = (const float*)d_in[2];
  const float* WV = (const float*)d_in[3];
  const float* WO = (const float*)d_in[4];
  float* out = (float*)d_out;

  const size_t MTOK = (size_t)4 * SEQ;        // 8192 rows
  const size_t NTOK = MTOK * EMB;             // 8,388,608 elements

  const size_t NEEDED = 4 * NTOK * sizeof(u16);   // 64 MiB: Q,K,VT,Ob (bf16)
  if (ws_size < NEEDED) {
    fill_sig<<<dim3((out_size + 255) / 256), 256, 0, stream>>>(out, out_size);
    return;
  }

  u16* ws  = (u16*)d_ws;
  u16* Qb  = ws;
  u16* Kb  = Qb + NTOK;
  u16* VTb = Kb + NTOK;
  u16* Ob  = VTb + NTOK;

  gemm_qkv<<<dim3(MTOK / 128, EMB / 128, 3), 256, 0, stream>>>(
      x, WQ, WK, WV, Qb, Kb, VTb);
  attn64<<<dim3(SEQ / 64, 4 * NH), 256, 0, stream>>>(Qb, Kb, VTb, Ob);
  gemm_out<<<dim3(MTOK / 128, EMB / 128), 256, 0, stream>>>(Ob, WO, out);
}

// Round 7
// 337.593 us; speedup vs baseline: 1.7502x; 1.6260x over previous
//
#include <hip/hip_runtime.h>

typedef unsigned short u16;
typedef short bf16x8 __attribute__((ext_vector_type(8)));
typedef float f32x4 __attribute__((ext_vector_type(4)));

// B=4, S=2048, E=1024, H=16, dk=64
#define SEQ   2048
#define EMB   1024
#define NH    16
#define DK    64

// softmax in base-2: Q pre-scaled by 0.125 * log2(e)
#define QSCALE 0.1803368801111144f

__device__ __forceinline__ u16 bf16_rne(float f) {
  union { float f; unsigned u; } x;
  x.f = f;
  unsigned u = x.u;
  u += 0x7fffu + ((u >> 16) & 1u);
  return (u16)(u >> 16);
}

// ---------------------------------------------------------------- fallback
__global__ __launch_bounds__(256) void fill_sig(float* __restrict__ out, int n) {
  const int i = blockIdx.x * 256 + threadIdx.x;
  if (i < n) out[i] = 1.0f;   // "workspace too small" signal
}

// ---------------------------------------------------------------- transpose+convert
// dst[n][k] = bf16(src[k][n]) ; 64x64 tiles, grid (16,16)
__global__ __launch_bounds__(256) void tcvt(const float* __restrict__ src,
                                            u16* __restrict__ dst) {
  __shared__ u16 tile[64][65];
  const int bx = blockIdx.x * 64, by = blockIdx.y * 64;
  for (int i = threadIdx.x; i < 64 * 64; i += 256) {
    const int r = i >> 6, c = i & 63;
    tile[c][r] = bf16_rne(src[(size_t)(by + r) * EMB + bx + c]);
  }
  __syncthreads();
  for (int i = threadIdx.x; i < 64 * 64; i += 256) {
    const int r = i >> 6, c = i & 63;
    dst[(size_t)(bx + r) * EMB + by + c] = tile[r][c];
  }
}

// ---------------------------------------------------------------- QKV GEMM
// C_z[M,1024] = x[M,1024] @ W_z ; A f32 (convert in regs), B bf16 W^T via DMA.
// z==0 (Q): head layout [((b*16+h)*2048+s)*64+d], scaled by QSCALE
// z==1 (K): head layout, unscaled
// z==2 (V): transposed layout [((b*16+h)*64+d)*2048 + s] via LDS transpose
__global__ __launch_bounds__(256) void gemm_qkv(
    const float* __restrict__ A,
    const u16* __restrict__ T0, const u16* __restrict__ T1, const u16* __restrict__ T2,
    u16* __restrict__ C0, u16* __restrict__ C1, u16* __restrict__ C2)
{
  const int z = blockIdx.z;
  const u16* Wt = (z == 0) ? T0 : (z == 1) ? T1 : T2;
  u16* C = (z == 0) ? C0 : (z == 1) ? C1 : C2;
  const float scale = (z == 0) ? QSCALE : 1.0f;

  __shared__ __align__(16) u16 sh[8704];   // As(4096)+Bs(4096); reused as T(64*136)
  u16* const As = sh;
  u16* const Bs = sh + 4096;

  const int tid  = threadIdx.x;
  const int lane = tid & 63;
  const int w    = tid >> 6;
  const int wm   = (w >> 1) * 64;
  const int wn   = (w & 1) * 64;
  const int m0   = blockIdx.x * 128;
  const int n0   = blockIdx.y * 128;

  const int l15  = lane & 15;
  const int g8   = (lane >> 4) * 8;

  const int srow0 = tid >> 2;           // 0..63
  const int skc   = (tid & 3) * 8;      // f32 col offset

  const int lrow = lane >> 2;           // DMA: row within 16-row chunk
  const int lcol = (lane & 3) * 8;      // DMA: col offset

  f32x4 acc[4][4] = {};

  for (int k0 = 0; k0 < 1024; k0 += 32) {
    // ---- B: global->LDS DMA (bf16 W^T)
#pragma unroll
    for (int i = 0; i < 2; ++i) {
      const int r = w * 32 + i * 16;
      const u16* gb = Wt + (size_t)(n0 + r + lrow) * 1024 + (k0 + lcol);
      __builtin_amdgcn_global_load_lds((const __attribute__((address_space(1))) void*)gb,
                                       (__attribute__((address_space(3))) void*)(Bs + r * 32), 16, 0, 0);
    }
    // ---- A: f32 load + convert + LDS store
    float4 a00 = *(const float4*)(A + (size_t)(m0 + srow0) * 1024 + k0 + skc);
    float4 a01 = *(const float4*)(A + (size_t)(m0 + srow0) * 1024 + k0 + skc + 4);
    float4 a10 = *(const float4*)(A + (size_t)(m0 + srow0 + 64) * 1024 + k0 + skc);
    float4 a11 = *(const float4*)(A + (size_t)(m0 + srow0 + 64) * 1024 + k0 + skc + 4);
    union { int4 v; u16 h[8]; } c0, c1;
    c0.h[0] = bf16_rne(a00.x); c0.h[1] = bf16_rne(a00.y);
    c0.h[2] = bf16_rne(a00.z); c0.h[3] = bf16_rne(a00.w);
    c0.h[4] = bf16_rne(a01.x); c0.h[5] = bf16_rne(a01.y);
    c0.h[6] = bf16_rne(a01.z); c0.h[7] = bf16_rne(a01.w);
    c1.h[0] = bf16_rne(a10.x); c1.h[1] = bf16_rne(a10.y);
    c1.h[2] = bf16_rne(a10.z); c1.h[3] = bf16_rne(a10.w);
    c1.h[4] = bf16_rne(a11.x); c1.h[5] = bf16_rne(a11.y);
    c1.h[6] = bf16_rne(a11.z); c1.h[7] = bf16_rne(a11.w);
    *(int4*)(As + srow0 * 32 + skc) = c0.v;
    *(int4*)(As + (srow0 + 64) * 32 + skc) = c1.v;

    __syncthreads();
    bf16x8 a[4], b[4];
#pragma unroll
    for (int mi = 0; mi < 4; ++mi)
      a[mi] = *(const bf16x8*)(As + (wm + mi * 16 + l15) * 32 + g8);
#pragma unroll
    for (int ni = 0; ni < 4; ++ni)
      b[ni] = *(const bf16x8*)(Bs + (wn + ni * 16 + l15) * 32 + g8);
#pragma unroll
    for (int mi = 0; mi < 4; ++mi)
#pragma unroll
      for (int ni = 0; ni < 4; ++ni)
        acc[mi][ni] = __builtin_amdgcn_mfma_f32_16x16x32_bf16(a[mi], b[ni], acc[mi][ni], 0, 0, 0);
    __syncthreads();
  }

  const int rb = (lane >> 4) * 4;

  if (z != 2) {
#pragma unroll
    for (int mi = 0; mi < 4; ++mi) {
#pragma unroll
      for (int r = 0; r < 4; ++r) {
        const int row = m0 + wm + mi * 16 + rb + r;
        const int bb = row >> 11, s = row & 2047;
#pragma unroll
        for (int ni = 0; ni < 4; ++ni) {
          const int col = n0 + wn + ni * 16 + l15;
          const int hh = col >> 6, d = col & 63;
          C[((size_t)(bb * NH + hh) * SEQ + s) * DK + d] = bf16_rne(acc[mi][ni][r] * scale);
        }
      }
    }
  } else {
    // V: transposed write via LDS (tile covers heads (n0>>6)+{0,1})
    const int bb = m0 >> 11;
    const int s0 = m0 & 2047;
    u16* const T = sh;   // 64 x 136, XOR-swizzled along s
    const int dRd  = tid >> 2;
    const int cbRd = (tid & 3) * 32;
    const int swzR = ((dRd >> 3) & 7) << 3;
#pragma unroll
    for (int p = 0; p < 2; ++p) {
      if ((w & 1) == p) {
#pragma unroll
        for (int mi = 0; mi < 4; ++mi)
#pragma unroll
          for (int r = 0; r < 4; ++r) {
            const int s_local = wm + mi * 16 + rb + r;
#pragma unroll
            for (int ni = 0; ni < 4; ++ni) {
              const int d = ni * 16 + l15;
              T[d * 136 + (s_local ^ (((d >> 3) & 7) << 3))] = bf16_rne(acc[mi][ni][r]);
            }
          }
      }
      __syncthreads();
      u16* dst = C + ((size_t)(bb * NH + (n0 >> 6) + p) * DK + dRd) * SEQ + s0 + cbRd;
#pragma unroll
      for (int k = 0; k < 4; ++k) {
        int4 v = *(const int4*)(T + dRd * 136 + ((cbRd + 8 * k) ^ swzR));
        *(int4*)(dst + 8 * k) = v;
      }
      __syncthreads();
    }
  }
}

// ---------------------------------------------------------------- out GEMM
// out[M,1024] (f32) = Ob[M,1024] (bf16) @ WO ; both sides via DMA (WOt bf16)
__global__ __launch_bounds__(256) void gemm_out(
    const u16* __restrict__ A, const u16* __restrict__ Wt, float* __restrict__ C)
{
  __shared__ __align__(16) u16 As[128 * 32];
  __shared__ __align__(16) u16 Bs[128 * 32];

  const int tid  = threadIdx.x;
  const int lane = tid & 63;
  const int w    = tid >> 6;
  const int wm   = (w >> 1) * 64;
  const int wn   = (w & 1) * 64;
  const int m0   = blockIdx.x * 128;
  const int n0   = blockIdx.y * 128;

  const int l15  = lane & 15;
  const int g8   = (lane >> 4) * 8;

  const int lrow = lane >> 2;
  const int lcol = (lane & 3) * 8;

  f32x4 acc[4][4] = {};

  for (int k0 = 0; k0 < 1024; k0 += 32) {
#pragma unroll
    for (int i = 0; i < 2; ++i) {
      const int r = w * 32 + i * 16;
      const u16* ga = A  + (size_t)(m0 + r + lrow) * 1024 + (k0 + lcol);
      const u16* gb = Wt + (size_t)(n0 + r + lrow) * 1024 + (k0 + lcol);
      __builtin_amdgcn_global_load_lds((const __attribute__((address_space(1))) void*)ga,
                                       (__attribute__((address_space(3))) void*)(As + r * 32), 16, 0, 0);
      __builtin_amdgcn_global_load_lds((const __attribute__((address_space(1))) void*)gb,
                                       (__attribute__((address_space(3))) void*)(Bs + r * 32), 16, 0, 0);
    }
    __syncthreads();
    bf16x8 a[4], b[4];
#pragma unroll
    for (int mi = 0; mi < 4; ++mi)
      a[mi] = *(const bf16x8*)(As + (wm + mi * 16 + l15) * 32 + g8);
#pragma unroll
    for (int ni = 0; ni < 4; ++ni)
      b[ni] = *(const bf16x8*)(Bs + (wn + ni * 16 + l15) * 32 + g8);
#pragma unroll
    for (int mi = 0; mi < 4; ++mi)
#pragma unroll
      for (int ni = 0; ni < 4; ++ni)
        acc[mi][ni] = __builtin_amdgcn_mfma_f32_16x16x32_bf16(a[mi], b[ni], acc[mi][ni], 0, 0, 0);
    __syncthreads();
  }

  const int rb = (lane >> 4) * 4;
#pragma unroll
  for (int mi = 0; mi < 4; ++mi) {
#pragma unroll
    for (int r = 0; r < 4; ++r) {
      const int row = m0 + wm + mi * 16 + rb + r;
#pragma unroll
      for (int ni = 0; ni < 4; ++ni) {
        const int col = n0 + wn + ni * 16 + l15;
        C[(size_t)row * 1024 + col] = acc[mi][ni][r];
      }
    }
  }
}

// ---------------------------------------------------------------- attention
// Q,K: [B*H, S, 64] bf16 (Q pre-scaled, base-2). VT: [B*H, 64, S]. O: [B*S, E].
// Grid (16, 64): block handles q-tile pair (it, 31-it) = constant 33 iterations.
// K,V tiles staged cooperatively in LDS; next tile prefetched into registers.
__global__ __launch_bounds__(256) void attn64(
    const u16* __restrict__ Q, const u16* __restrict__ K, const u16* __restrict__ VT,
    u16* __restrict__ O)
{
  const int it  = blockIdx.x;        // 0..15
  const int bh  = blockIdx.y;
  const int tid = threadIdx.x;
  const int lane = tid & 63;
  const int w    = tid >> 6;

  const u16* Qp = Q  + (size_t)bh * SEQ * DK;
  const u16* Kp = K  + (size_t)bh * SEQ * DK;
  const u16* Vp = VT + (size_t)bh * DK * SEQ;   // [d][s]

  __shared__ __align__(16) u16 Ks[64 * 72];     // [key][d]
  __shared__ __align__(16) u16 Vs[64 * 72];     // [d][key]
  __shared__ __align__(16) u16 Pt[4][16 * 72];  // per-wave [q][key]

  const int l15 = lane & 15;
  const int g   = lane >> 4;
  const int g8  = g * 8;

  // cooperative staging map: thread covers rows (tid>>3), (tid>>3)+32; 16B each
  const int srow = tid >> 3;        // 0..31
  const int sc8  = (tid & 7) * 8;   // 0..56
  const u16* kb = Kp + (size_t)srow * DK + sc8;      // + t*64*DK ; +32*DK
  const u16* vb = Vp + (size_t)srow * SEQ + sc8;     // + t*64    ; +32*SEQ
  u16* const ksd0 = Ks + srow * 72 + sc8;
  u16* const ksd1 = Ks + (srow + 32) * 72 + sc8;
  u16* const vsd0 = Vs + srow * 72 + sc8;
  u16* const vsd1 = Vs + (srow + 32) * 72 + sc8;

  u16* const pw = &Pt[w][0];
  const int b_ = bh >> 4, h_ = bh & 15;

  int4 kr0, kr1, vr0, vr1;

  for (int pass = 0; pass < 2; ++pass) {
    const int qt = pass ? 31 - it : it;
    const int q0 = qt * 64 + w * 16;

    bf16x8 qf[2];
#pragma unroll
    for (int kk = 0; kk < 2; ++kk)
      qf[kk] = *(const bf16x8*)(Qp + (size_t)(q0 + l15) * DK + kk * 32 + g8);

    f32x4 o[4] = {};                   // O[16 q][64 d], C-layout (row=q=g*4+r)
    float mrun = -1e30f, lrun = 0.f;   // stats for q = q0 + l15 (base-2)

    // prefetch tile 0
    kr0 = *(const int4*)(kb);
    kr1 = *(const int4*)(kb + (size_t)32 * DK);
    vr0 = *(const int4*)(vb);
    vr1 = *(const int4*)(vb + (size_t)32 * SEQ);

    for (int t = 0; t <= qt; ++t) {
      __syncthreads();                 // prior-iter/pass LDS reads complete
      *(int4*)ksd0 = kr0; *(int4*)ksd1 = kr1;
      *(int4*)vsd0 = vr0; *(int4*)vsd1 = vr1;
      __syncthreads();                 // staging visible
      if (t < qt) {                    // issue next tile's loads now
        const u16* kn = kb + (size_t)(t + 1) * 64 * DK;
        const u16* vn = vb + (t + 1) * 64;
        kr0 = *(const int4*)(kn);
        kr1 = *(const int4*)(kn + (size_t)32 * DK);
        vr0 = *(const int4*)(vn);
        vr1 = *(const int4*)(vn + (size_t)32 * SEQ);
      }

      // ---- S^T = K . Q^T : m=key (4x16), n=q (16)
      f32x4 st[4] = {};
#pragma unroll
      for (int kk = 0; kk < 2; ++kk) {
#pragma unroll
        for (int mt = 0; mt < 4; ++mt) {
          const bf16x8 kf = *(const bf16x8*)(Ks + (mt * 16 + l15) * 72 + kk * 32 + g8);
          st[mt] = __builtin_amdgcn_mfma_f32_16x16x32_bf16(kf, qf[kk], st[mt], 0, 0, 0);
        }
      }

      if (t == qt) {                   // causal mask on diagonal tile
        const int qrow = q0 + l15;
#pragma unroll
        for (int mt = 0; mt < 4; ++mt)
#pragma unroll
          for (int r = 0; r < 4; ++r)
            if (qt * 64 + mt * 16 + g * 4 + r > qrow) st[mt][r] = -1e30f;
      }

      // ---- online softmax (base-2), stats per q = l15
      float tmax = -1e30f;
#pragma unroll
      for (int mt = 0; mt < 4; ++mt)
#pragma unroll
        for (int r = 0; r < 4; ++r) tmax = fmaxf(tmax, st[mt][r]);
      tmax = fmaxf(tmax, __shfl_xor(tmax, 16));
      tmax = fmaxf(tmax, __shfl_xor(tmax, 32));

      const float mnew  = fmaxf(mrun, tmax);
      const float alpha = exp2f(mrun - mnew);
      mrun = mnew;

      float psum = 0.f;
#pragma unroll
      for (int mt = 0; mt < 4; ++mt) {
        float p0 = exp2f(st[mt][0] - mnew);
        float p1 = exp2f(st[mt][1] - mnew);
        float p2 = exp2f(st[mt][2] - mnew);
        float p3 = exp2f(st[mt][3] - mnew);
        psum += (p0 + p1) + (p2 + p3);
        uint2 pk;
        pk.x = (unsigned)bf16_rne(p0) | ((unsigned)bf16_rne(p1) << 16);
        pk.y = (unsigned)bf16_rne(p2) | ((unsigned)bf16_rne(p3) << 16);
        *(uint2*)(pw + l15 * 72 + mt * 16 + g * 4) = pk;   // P[q=l15][key]
      }
      psum += __shfl_xor(psum, 16);
      psum += __shfl_xor(psum, 32);
      lrun = lrun * alpha + psum;

      // rescale O (alpha indexed by q=l15; O rows are q=g*4+r)
#pragma unroll
      for (int r = 0; r < 4; ++r) {
        const float ar = __shfl(alpha, g * 4 + r);
#pragma unroll
        for (int nt = 0; nt < 4; ++nt) o[nt][r] *= ar;
      }

      // ---- O += P . V  (Pt same-wave RAW: lgkmcnt only, no barrier)
#pragma unroll
      for (int kk = 0; kk < 2; ++kk) {
        const bf16x8 pa = *(const bf16x8*)(pw + l15 * 72 + kk * 32 + g8);
#pragma unroll
        for (int nt = 0; nt < 4; ++nt) {
          const bf16x8 vv = *(const bf16x8*)(Vs + (nt * 16 + l15) * 72 + kk * 32 + g8);
          o[nt] = __builtin_amdgcn_mfma_f32_16x16x32_bf16(pa, vv, o[nt], 0, 0, 0);
        }
      }
    }

    // epilogue: O[q][d] / l  -> Ob[b][s][h*64+d]
#pragma unroll
    for (int r = 0; r < 4; ++r) {
      const float lr  = __shfl(lrun, g * 4 + r);
      const float inv = 1.0f / lr;
      const int   s   = q0 + g * 4 + r;
#pragma unroll
      for (int nt = 0; nt < 4; ++nt) {
        const int d = nt * 16 + l15;
        O[((size_t)b_ * SEQ + s) * EMB + h_ * DK + d] = bf16_rne(o[nt][r] * inv);
      }
    }
  }
}

// ---------------------------------------------------------------- launch
extern "C" void kernel_launch(void* const* d_in, const int* in_sizes, int n_in,
                              void* d_out, int out_size, void* d_ws, size_t ws_size,
                              hipStream_t stream) {
  (void)in_sizes; (void)n_in;
  const float* x  = (const float*)d_in[0];
  const float* WQ = (const float*)d_in[1];
  const float* WK = (const float*)d_in[2];
  const float* WV = (const float*)d_in[3];
  const float* WO = (const float*)d_in[4];
  float* out = (float*)d_out;

  const size_t MTOK = (size_t)4 * SEQ;        // 8192 rows
  const size_t NTOK = MTOK * EMB;             // 8,388,608 elements
  const size_t NW   = (size_t)EMB * EMB;      // 1,048,576 elements

  const size_t NEEDED = 4 * NTOK * sizeof(u16);   // 64 MiB: Q,K,VT,Ob (bf16)
  if (ws_size < NEEDED) {
    fill_sig<<<dim3((out_size + 255) / 256), 256, 0, stream>>>(out, out_size);
    return;
  }

  u16* ws  = (u16*)d_ws;
  u16* Qb  = ws;
  u16* Kb  = Qb + NTOK;
  u16* VTb = Kb + NTOK;
  u16* Ob  = VTb + NTOK;
  // transposed bf16 weights live in dead regions:
  u16* WQt = Ob;            // Ob not written until attn64
  u16* WKt = WQt + NW;
  u16* WVt = WKt + NW;
  u16* WOt = Qb;            // Qb dead after attn64

  tcvt<<<dim3(16, 16), 256, 0, stream>>>(WQ, WQt);
  tcvt<<<dim3(16, 16), 256, 0, stream>>>(WK, WKt);
  tcvt<<<dim3(16, 16), 256, 0, stream>>>(WV, WVt);
  gemm_qkv<<<dim3(MTOK / 128, EMB / 128, 3), 256, 0, stream>>>(
      x, WQt, WKt, WVt, Qb, Kb, VTb);
  attn64<<<dim3(16, 4 * NH), 256, 0, stream>>>(Qb, Kb, VTb, Ob);
  tcvt<<<dim3(16, 16), 256, 0, stream>>>(WO, WOt);
  gemm_out<<<dim3(MTOK / 128, EMB / 128), 256, 0, stream>>>(Ob, WOt, out);
}

// Round 8
// 306.202 us; speedup vs baseline: 1.9296x; 1.1025x over previous
//
#include <hip/hip_runtime.h>

typedef unsigned short u16;
typedef short bf16x8 __attribute__((ext_vector_type(8)));
typedef float f32x4 __attribute__((ext_vector_type(4)));

// B=4, S=2048, E=1024, H=16, dk=64
#define SEQ   2048
#define EMB   1024
#define NH    16
#define DK    64

// softmax in base-2: Q path pre-scaled by 0.125 * log2(e)  (baked into WQt)
#define QSCALE 0.1803368801111144f

__device__ __forceinline__ u16 bf16_rne(float f) {
  union { float f; unsigned u; } x;
  x.f = f;
  unsigned u = x.u;
  u += 0x7fffu + ((u >> 16) & 1u);
  return (u16)(u >> 16);
}

// ---------------------------------------------------------------- fallback
__global__ __launch_bounds__(256) void fill_sig(float* __restrict__ out, int n) {
  const int i = blockIdx.x * 256 + threadIdx.x;
  if (i < n) out[i] = 1.0f;   // "workspace too small" signal
}

// ---------------------------------------------------------------- x -> bf16
// xb[i] = bf16(x[i]), 8 elems/thread
__global__ __launch_bounds__(256) void cvt_x(const float* __restrict__ x,
                                             u16* __restrict__ xb) {
  const size_t i = ((size_t)blockIdx.x * 256 + threadIdx.x) * 8;
  float4 v0 = *(const float4*)(x + i);
  float4 v1 = *(const float4*)(x + i + 4);
  union { int4 v; u16 h[8]; } c;
  c.h[0] = bf16_rne(v0.x); c.h[1] = bf16_rne(v0.y);
  c.h[2] = bf16_rne(v0.z); c.h[3] = bf16_rne(v0.w);
  c.h[4] = bf16_rne(v1.x); c.h[5] = bf16_rne(v1.y);
  c.h[6] = bf16_rne(v1.z); c.h[7] = bf16_rne(v1.w);
  *(int4*)(xb + i) = c.v;
}

// ---------------------------------------------------------------- transpose+convert
// dst_z[n][k] = bf16(src_z[k][n] * scale_z) ; 64x64 tiles, grid (16,16,nz)
__global__ __launch_bounds__(256) void tcvt3(
    const float* __restrict__ s0, const float* __restrict__ s1, const float* __restrict__ s2,
    u16* __restrict__ d0, u16* __restrict__ d1, u16* __restrict__ d2) {
  const int z = blockIdx.z;
  const float* src = (z == 0) ? s0 : (z == 1) ? s1 : s2;
  u16* dst = (z == 0) ? d0 : (z == 1) ? d1 : d2;
  const float sc = (z == 0) ? QSCALE : 1.0f;
  __shared__ u16 tile[64][65];
  const int bx = blockIdx.x * 64, by = blockIdx.y * 64;
  for (int i = threadIdx.x; i < 64 * 64; i += 256) {
    const int r = i >> 6, c = i & 63;
    tile[c][r] = bf16_rne(src[(size_t)(by + r) * EMB + bx + c] * sc);
  }
  __syncthreads();
  for (int i = threadIdx.x; i < 64 * 64; i += 256) {
    const int r = i >> 6, c = i & 63;
    dst[(size_t)(bx + r) * EMB + by + c] = tile[r][c];
  }
}

__global__ __launch_bounds__(256) void tcvt1(const float* __restrict__ src,
                                             u16* __restrict__ dst) {
  __shared__ u16 tile[64][65];
  const int bx = blockIdx.x * 64, by = blockIdx.y * 64;
  for (int i = threadIdx.x; i < 64 * 64; i += 256) {
    const int r = i >> 6, c = i & 63;
    tile[c][r] = bf16_rne(src[(size_t)(by + r) * EMB + bx + c]);
  }
  __syncthreads();
  for (int i = threadIdx.x; i < 64 * 64; i += 256) {
    const int r = i >> 6, c = i & 63;
    dst[(size_t)(bx + r) * EMB + by + c] = tile[r][c];
  }
}

// ---------------------------------------------------------------- QKV GEMM
// C_z[M,1024] = xb[M,1024] @ W_z^T^T ; both operands bf16 via DMA.
// z==0 (Q, pre-scaled): head layout [((b*16+h)*2048+s)*64+d]
// z==1 (K): head layout
// z==2 (V): transposed layout [((b*16+h)*64+d)*2048 + s] via LDS transpose
__global__ __launch_bounds__(256) void gemm_qkv(
    const u16* __restrict__ A,
    const u16* __restrict__ T0, const u16* __restrict__ T1, const u16* __restrict__ T2,
    u16* __restrict__ C0, u16* __restrict__ C1, u16* __restrict__ C2)
{
  const int z = blockIdx.z;
  const u16* Wt = (z == 0) ? T0 : (z == 1) ? T1 : T2;
  u16* C = (z == 0) ? C0 : (z == 1) ? C1 : C2;

  __shared__ __align__(16) u16 sh[8704];   // As(4096)+Bs(4096); reused as T(64*136)
  u16* const As = sh;
  u16* const Bs = sh + 4096;

  const int tid  = threadIdx.x;
  const int lane = tid & 63;
  const int w    = tid >> 6;
  const int wm   = (w >> 1) * 64;
  const int wn   = (w & 1) * 64;
  const int m0   = blockIdx.x * 128;
  const int n0   = blockIdx.y * 128;

  const int l15  = lane & 15;
  const int g8   = (lane >> 4) * 8;

  const int lrow = lane >> 2;           // DMA: row within 16-row chunk
  const int lcol = (lane & 3) * 8;      // DMA: col offset

  f32x4 acc[4][4] = {};

  for (int k0 = 0; k0 < 1024; k0 += 32) {
#pragma unroll
    for (int i = 0; i < 2; ++i) {
      const int r = w * 32 + i * 16;
      const u16* ga = A  + (size_t)(m0 + r + lrow) * 1024 + (k0 + lcol);
      const u16* gb = Wt + (size_t)(n0 + r + lrow) * 1024 + (k0 + lcol);
      __builtin_amdgcn_global_load_lds((const __attribute__((address_space(1))) void*)ga,
                                       (__attribute__((address_space(3))) void*)(As + r * 32), 16, 0, 0);
      __builtin_amdgcn_global_load_lds((const __attribute__((address_space(1))) void*)gb,
                                       (__attribute__((address_space(3))) void*)(Bs + r * 32), 16, 0, 0);
    }
    __syncthreads();
    bf16x8 a[4], b[4];
#pragma unroll
    for (int mi = 0; mi < 4; ++mi)
      a[mi] = *(const bf16x8*)(As + (wm + mi * 16 + l15) * 32 + g8);
#pragma unroll
    for (int ni = 0; ni < 4; ++ni)
      b[ni] = *(const bf16x8*)(Bs + (wn + ni * 16 + l15) * 32 + g8);
#pragma unroll
    for (int mi = 0; mi < 4; ++mi)
#pragma unroll
      for (int ni = 0; ni < 4; ++ni)
        acc[mi][ni] = __builtin_amdgcn_mfma_f32_16x16x32_bf16(a[mi], b[ni], acc[mi][ni], 0, 0, 0);
    __syncthreads();
  }

  const int rb = (lane >> 4) * 4;

  if (z != 2) {
#pragma unroll
    for (int mi = 0; mi < 4; ++mi) {
#pragma unroll
      for (int r = 0; r < 4; ++r) {
        const int row = m0 + wm + mi * 16 + rb + r;
        const int bb = row >> 11, s = row & 2047;
#pragma unroll
        for (int ni = 0; ni < 4; ++ni) {
          const int col = n0 + wn + ni * 16 + l15;
          const int hh = col >> 6, d = col & 63;
          C[((size_t)(bb * NH + hh) * SEQ + s) * DK + d] = bf16_rne(acc[mi][ni][r]);
        }
      }
    }
  } else {
    // V: transposed write via LDS (tile covers heads (n0>>6)+{0,1})
    const int bb = m0 >> 11;
    const int s0 = m0 & 2047;
    u16* const T = sh;   // 64 x 136, XOR-swizzled along s
    const int dRd  = tid >> 2;
    const int cbRd = (tid & 3) * 32;
    const int swzR = ((dRd >> 3) & 7) << 3;
#pragma unroll
    for (int p = 0; p < 2; ++p) {
      if ((w & 1) == p) {
#pragma unroll
        for (int mi = 0; mi < 4; ++mi)
#pragma unroll
          for (int r = 0; r < 4; ++r) {
            const int s_local = wm + mi * 16 + rb + r;
#pragma unroll
            for (int ni = 0; ni < 4; ++ni) {
              const int d = ni * 16 + l15;
              T[d * 136 + (s_local ^ (((d >> 3) & 7) << 3))] = bf16_rne(acc[mi][ni][r]);
            }
          }
      }
      __syncthreads();
      u16* dst = C + ((size_t)(bb * NH + (n0 >> 6) + p) * DK + dRd) * SEQ + s0 + cbRd;
#pragma unroll
      for (int k = 0; k < 4; ++k) {
        int4 v = *(const int4*)(T + dRd * 136 + ((cbRd + 8 * k) ^ swzR));
        *(int4*)(dst + 8 * k) = v;
      }
      __syncthreads();
    }
  }
}

// ---------------------------------------------------------------- out GEMM
// out[M,1024] (f32) = Ob[M,1024] (bf16) @ WO ; both sides via DMA (WOt bf16)
__global__ __launch_bounds__(256) void gemm_out(
    const u16* __restrict__ A, const u16* __restrict__ Wt, float* __restrict__ C)
{
  __shared__ __align__(16) u16 As[128 * 32];
  __shared__ __align__(16) u16 Bs[128 * 32];

  const int tid  = threadIdx.x;
  const int lane = tid & 63;
  const int w    = tid >> 6;
  const int wm   = (w >> 1) * 64;
  const int wn   = (w & 1) * 64;
  const int m0   = blockIdx.x * 128;
  const int n0   = blockIdx.y * 128;

  const int l15  = lane & 15;
  const int g8   = (lane >> 4) * 8;

  const int lrow = lane >> 2;
  const int lcol = (lane & 3) * 8;

  f32x4 acc[4][4] = {};

  for (int k0 = 0; k0 < 1024; k0 += 32) {
#pragma unroll
    for (int i = 0; i < 2; ++i) {
      const int r = w * 32 + i * 16;
      const u16* ga = A  + (size_t)(m0 + r + lrow) * 1024 + (k0 + lcol);
      const u16* gb = Wt + (size_t)(n0 + r + lrow) * 1024 + (k0 + lcol);
      __builtin_amdgcn_global_load_lds((const __attribute__((address_space(1))) void*)ga,
                                       (__attribute__((address_space(3))) void*)(As + r * 32), 16, 0, 0);
      __builtin_amdgcn_global_load_lds((const __attribute__((address_space(1))) void*)gb,
                                       (__attribute__((address_space(3))) void*)(Bs + r * 32), 16, 0, 0);
    }
    __syncthreads();
    bf16x8 a[4], b[4];
#pragma unroll
    for (int mi = 0; mi < 4; ++mi)
      a[mi] = *(const bf16x8*)(As + (wm + mi * 16 + l15) * 32 + g8);
#pragma unroll
    for (int ni = 0; ni < 4; ++ni)
      b[ni] = *(const bf16x8*)(Bs + (wn + ni * 16 + l15) * 32 + g8);
#pragma unroll
    for (int mi = 0; mi < 4; ++mi)
#pragma unroll
      for (int ni = 0; ni < 4; ++ni)
        acc[mi][ni] = __builtin_amdgcn_mfma_f32_16x16x32_bf16(a[mi], b[ni], acc[mi][ni], 0, 0, 0);
    __syncthreads();
  }

  const int rb = (lane >> 4) * 4;
#pragma unroll
  for (int mi = 0; mi < 4; ++mi) {
#pragma unroll
    for (int r = 0; r < 4; ++r) {
      const int row = m0 + wm + mi * 16 + rb + r;
#pragma unroll
      for (int ni = 0; ni < 4; ++ni) {
        const int col = n0 + wn + ni * 16 + l15;
        C[(size_t)row * 1024 + col] = acc[mi][ni][r];
      }
    }
  }
}

// ---------------------------------------------------------------- attention
// Q,K: [B*H, S, 64] bf16 (Q pre-scaled, base-2). VT: [B*H, 64, S]. O: [B*S, E].
// Grid (8, 64): block handles 128-row q-tile pair (it, 15-it) = 36 iterations.
// Wave w owns 32 q-rows (2 MFMA row-groups); K/V frags shared across groups.
__global__ __launch_bounds__(256) void attn64(
    const u16* __restrict__ Q, const u16* __restrict__ K, const u16* __restrict__ VT,
    u16* __restrict__ O)
{
  const int it  = blockIdx.x;        // 0..7
  const int bh  = blockIdx.y;
  const int tid = threadIdx.x;
  const int lane = tid & 63;
  const int w    = tid >> 6;

  const u16* Qp = Q  + (size_t)bh * SEQ * DK;
  const u16* Kp = K  + (size_t)bh * SEQ * DK;
  const u16* Vp = VT + (size_t)bh * DK * SEQ;   // [d][s]

  __shared__ __align__(16) u16 Ks[64 * 72];     // [key][d]
  __shared__ __align__(16) u16 Vs[64 * 72];     // [d][key]
  __shared__ __align__(16) u16 Pt[4][32 * 72];  // per-wave [q(32)][key]

  const int l15 = lane & 15;
  const int g   = lane >> 4;
  const int g8  = g * 8;

  // cooperative staging map: thread covers rows (tid>>3), (tid>>3)+32; 16B each
  const int srow = tid >> 3;        // 0..31
  const int sc8  = (tid & 7) * 8;   // 0..56
  const u16* kb = Kp + (size_t)srow * DK + sc8;      // + t*64*DK ; +32*DK
  const u16* vb = Vp + (size_t)srow * SEQ + sc8;     // + t*64    ; +32*SEQ
  u16* const ksd0 = Ks + srow * 72 + sc8;
  u16* const ksd1 = Ks + (srow + 32) * 72 + sc8;
  u16* const vsd0 = Vs + srow * 72 + sc8;
  u16* const vsd1 = Vs + (srow + 32) * 72 + sc8;

  u16* const pw = &Pt[w][0];
  const int b_ = bh >> 4, h_ = bh & 15;

  int4 kr0, kr1, vr0, vr1;

  for (int pass = 0; pass < 2; ++pass) {
    const int qt = pass ? 15 - it : it;   // 128-row q-tile index, 0..15
    const int q0 = qt * 128;
    const int qw = q0 + w * 32;           // wave's 32 rows
    const int tlast = 2 * qt + 1;

    bf16x8 qf[2][2];
#pragma unroll
    for (int j = 0; j < 2; ++j)
#pragma unroll
      for (int kk = 0; kk < 2; ++kk)
        qf[j][kk] = *(const bf16x8*)(Qp + (size_t)(qw + j * 16 + l15) * DK + kk * 32 + g8);

    f32x4 o[2][4] = {};                   // per group: O[16 q][64 d], C-layout
    float mrun[2] = { -1e30f, -1e30f };
    float lrun[2] = { 0.f, 0.f };

    // prefetch tile 0
    kr0 = *(const int4*)(kb);
    kr1 = *(const int4*)(kb + (size_t)32 * DK);
    vr0 = *(const int4*)(vb);
    vr1 = *(const int4*)(vb + (size_t)32 * SEQ);

    for (int t = 0; t <= tlast; ++t) {
      __syncthreads();                 // prior-iter LDS reads complete
      *(int4*)ksd0 = kr0; *(int4*)ksd1 = kr1;
      *(int4*)vsd0 = vr0; *(int4*)vsd1 = vr1;
      __syncthreads();                 // staging visible
      if (t < tlast) {                 // issue next tile's loads now
        const u16* kn = kb + (size_t)(t + 1) * 64 * DK;
        const u16* vn = vb + (t + 1) * 64;
        kr0 = *(const int4*)(kn);
        kr1 = *(const int4*)(kn + (size_t)32 * DK);
        vr0 = *(const int4*)(vn);
        vr1 = *(const int4*)(vn + (size_t)32 * SEQ);
      }

      // wave-uniform activity: any of this wave's rows sees keys of tile t
      if (64 * t >= qw + 32) continue;   // (no barriers below in this iter)

      // ---- S^T = K . Q^T, both row-groups sharing the K frags
      f32x4 st[2][4] = {};
#pragma unroll
      for (int kk = 0; kk < 2; ++kk) {
#pragma unroll
        for (int mt = 0; mt < 4; ++mt) {
          const bf16x8 kf = *(const bf16x8*)(Ks + (mt * 16 + l15) * 72 + kk * 32 + g8);
          st[0][mt] = __builtin_amdgcn_mfma_f32_16x16x32_bf16(kf, qf[0][kk], st[0][mt], 0, 0, 0);
          st[1][mt] = __builtin_amdgcn_mfma_f32_16x16x32_bf16(kf, qf[1][kk], st[1][mt], 0, 0, 0);
        }
      }

#pragma unroll
      for (int j = 0; j < 2; ++j) {
        const int qg = qw + j * 16;
        if (qg <= 64 * t + 48) {       // diagonal overlap: apply causal mask
          const int qrow = qg + l15;
#pragma unroll
          for (int mt = 0; mt < 4; ++mt)
#pragma unroll
            for (int r = 0; r < 4; ++r)
              if (64 * t + mt * 16 + g * 4 + r > qrow) st[j][mt][r] = -1e30f;
        }

        // ---- online softmax (base-2), stats per q = qg + l15
        float tmax = -1e30f;
#pragma unroll
        for (int mt = 0; mt < 4; ++mt)
#pragma unroll
          for (int r = 0; r < 4; ++r) tmax = fmaxf(tmax, st[j][mt][r]);
        tmax = fmaxf(tmax, __shfl_xor(tmax, 16));
        tmax = fmaxf(tmax, __shfl_xor(tmax, 32));

        const float mnew  = fmaxf(mrun[j], tmax);
        const float alpha = exp2f(mrun[j] - mnew);
        mrun[j] = mnew;

        float psum = 0.f;
#pragma unroll
        for (int mt = 0; mt < 4; ++mt) {
          float p0 = exp2f(st[j][mt][0] - mnew);
          float p1 = exp2f(st[j][mt][1] - mnew);
          float p2 = exp2f(st[j][mt][2] - mnew);
          float p3 = exp2f(st[j][mt][3] - mnew);
          psum += (p0 + p1) + (p2 + p3);
          uint2 pk;
          pk.x = (unsigned)bf16_rne(p0) | ((unsigned)bf16_rne(p1) << 16);
          pk.y = (unsigned)bf16_rne(p2) | ((unsigned)bf16_rne(p3) << 16);
          *(uint2*)(pw + (j * 16 + l15) * 72 + mt * 16 + g * 4) = pk;
        }
        psum += __shfl_xor(psum, 16);
        psum += __shfl_xor(psum, 32);
        lrun[j] = lrun[j] * alpha + psum;

#pragma unroll
        for (int r = 0; r < 4; ++r) {
          const float ar = __shfl(alpha, g * 4 + r);
#pragma unroll
          for (int nt = 0; nt < 4; ++nt) o[j][nt][r] *= ar;
        }
      }

      // ---- O += P . V, V frags shared across groups (same-wave Pt RAW)
#pragma unroll
      for (int kk = 0; kk < 2; ++kk) {
        const bf16x8 pa0 = *(const bf16x8*)(pw + (0 + l15) * 72 + kk * 32 + g8);
        const bf16x8 pa1 = *(const bf16x8*)(pw + (16 + l15) * 72 + kk * 32 + g8);
#pragma unroll
        for (int nt = 0; nt < 4; ++nt) {
          const bf16x8 vv = *(const bf16x8*)(Vs + (nt * 16 + l15) * 72 + kk * 32 + g8);
          o[0][nt] = __builtin_amdgcn_mfma_f32_16x16x32_bf16(pa0, vv, o[0][nt], 0, 0, 0);
          o[1][nt] = __builtin_amdgcn_mfma_f32_16x16x32_bf16(pa1, vv, o[1][nt], 0, 0, 0);
        }
      }
    }

    // epilogue: O[q][d] / l  -> Ob[b][s][h*64+d]
#pragma unroll
    for (int j = 0; j < 2; ++j) {
#pragma unroll
      for (int r = 0; r < 4; ++r) {
        const float lr  = __shfl(lrun[j], g * 4 + r);
        const float inv = 1.0f / lr;
        const int   s   = qw + j * 16 + g * 4 + r;
#pragma unroll
        for (int nt = 0; nt < 4; ++nt) {
          const int d = nt * 16 + l15;
          O[((size_t)b_ * SEQ + s) * EMB + h_ * DK + d] = bf16_rne(o[j][nt][r] * inv);
        }
      }
    }
  }
}

// ---------------------------------------------------------------- launch
extern "C" void kernel_launch(void* const* d_in, const int* in_sizes, int n_in,
                              void* d_out, int out_size, void* d_ws, size_t ws_size,
                              hipStream_t stream) {
  (void)in_sizes; (void)n_in;
  const float* x  = (const float*)d_in[0];
  const float* WQ = (const float*)d_in[1];
  const float* WK = (const float*)d_in[2];
  const float* WV = (const float*)d_in[3];
  const float* WO = (const float*)d_in[4];
  float* out = (float*)d_out;

  const size_t MTOK = (size_t)4 * SEQ;        // 8192 rows
  const size_t NTOK = MTOK * EMB;             // 8,388,608 elements
  const size_t NW   = (size_t)EMB * EMB;      // 1,048,576 elements

  const size_t NEEDED = 4 * NTOK * sizeof(u16);   // 64 MiB: Q,K,VT,Ob (bf16)
  if (ws_size < NEEDED) {
    fill_sig<<<dim3((out_size + 255) / 256), 256, 0, stream>>>(out, out_size);
    return;
  }

  u16* ws  = (u16*)d_ws;
  u16* Qb  = ws;
  u16* Kb  = Qb + NTOK;
  u16* VTb = Kb + NTOK;
  u16* Ob  = VTb + NTOK;
  // scratch in dead regions:
  u16* xb  = (u16*)d_out;   // d_out (32MB f32) unused until gemm_out; xb = 16MB
  u16* WQt = Ob;            // Ob not written until attn64
  u16* WKt = WQt + NW;
  u16* WVt = WKt + NW;
  u16* WOt = Qb;            // Qb dead after attn64

  cvt_x<<<dim3(4096), 256, 0, stream>>>(x, xb);
  tcvt3<<<dim3(16, 16, 3), 256, 0, stream>>>(WQ, WK, WV, WQt, WKt, WVt);
  gemm_qkv<<<dim3(MTOK / 128, EMB / 128, 3), 256, 0, stream>>>(
      xb, WQt, WKt, WVt, Qb, Kb, VTb);
  attn64<<<dim3(8, 4 * NH), 256, 0, stream>>>(Qb, Kb, VTb, Ob);
  tcvt1<<<dim3(16, 16), 256, 0, stream>>>(WO, WOt);
  gemm_out<<<dim3(MTOK / 128, EMB / 128), 256, 0, stream>>>(Ob, WOt, out);
}